// Round 6
// baseline (7721.693 us; speedup 1.0000x reference)
//
#include <hip/hip_runtime.h>

// ---- problem constants ----
namespace {
constexpr int nT = 64;
constexpr int nK = 7;
constexpr long N_PSI = 1123776;
constexpr long SZ_WHH = 1048576;       // psi region 0: (1024,1024)
constexpr long REST_SZ = 75200;        // per-sample remaining psi elems
constexpr long R_BH = 0;               // (1024,)
constexpr long R_WIH = 1024;           // (8,1024)
constexpr long R_C = 9216;             // (1024,64)
constexpr long R_D = 74752;            // (8,56)
constexpr int NCHE = 16;               // encoder h-chunks per step
constexpr int CHRE = 64;               // rows per chunk (1024/16)
constexpr long PHALF_E = (long)NCHE * 64 * 1024;  // one encoder partial buffer (floats)
}

typedef __attribute__((ext_vector_type(4))) unsigned short us4;
typedef __attribute__((ext_vector_type(2))) unsigned short us2;

__device__ __forceinline__ float b2f(unsigned short u) {
  return __uint_as_float(((unsigned int)u) << 16);
}
__device__ __forceinline__ unsigned short f2b(float f) {
  unsigned int u = __float_as_uint(f);
  return (unsigned short)((u + 0x7fffu + ((u >> 16) & 1u)) >> 16);
}
__device__ __forceinline__ float sigm(float x) { return 1.f / (1.f + __expf(-x)); }

// ---------- one-time: transpose (rows,cols) fp32 -> bf16 out[c*rows + r] ----------
__global__ void transpose_bf16_k(const float* __restrict__ in, unsigned short* __restrict__ out,
                                 int rows, int cols) {
  __shared__ float tile[32][33];
  int x = blockIdx.x * 32 + threadIdx.x;
  int y = blockIdx.y * 32 + threadIdx.y;
  #pragma unroll
  for (int i = 0; i < 32; i += 8)
    if ((y + i) < rows && x < cols) tile[threadIdx.y + i][threadIdx.x] = in[(long)(y + i) * cols + x];
  __syncthreads();
  x = blockIdx.y * 32 + threadIdx.x;
  y = blockIdx.x * 32 + threadIdx.y;
  #pragma unroll
  for (int i = 0; i < 32; i += 8)
    if ((y + i) < cols && x < rows) out[(long)(y + i) * rows + x] = f2b(tile[threadIdx.x][threadIdx.y + i]);
}

__global__ void cvt_bf16_k(const float* __restrict__ in, unsigned short* __restrict__ out, long n) {
  long i = (long)blockIdx.x * 256 + threadIdx.x;
  if (i < n) out[i] = f2b(in[i]);
}

// ---------- bulk: encoder gx ----------
__global__ __launch_bounds__(256) void enc_gx_k(const float* __restrict__ outputs,
                                                const unsigned short* __restrict__ WtWihB,
                                                const float* __restrict__ bih,
                                                unsigned short* __restrict__ gxE) {
  int g0 = blockIdx.x * 256;           // 12 g-slices of 256 (3072)
  int btg = blockIdx.y;                // 64 groups of 64 bt items
  __shared__ unsigned short ws[64 * 256];   // 32 KB
  __shared__ float xs[64][64];              // 16 KB
  for (int i = threadIdx.x; i < 64 * 256; i += 256)
    ws[i] = WtWihB[(long)(i >> 8) * 3072 + g0 + (i & 255)];
  for (int i = threadIdx.x; i < 64 * 64; i += 256) {
    int idx = btg * 64 + (i >> 6);
    int t = idx >> 6, b = idx & 63;
    xs[i >> 6][i & 63] = outputs[((long)b * nT + t) * 64 + (i & 63)];
  }
  __syncthreads();
  float bihv = bih[g0 + threadIdx.x];
  for (int j = 0; j < 64; ++j) {
    int idx = btg * 64 + j;
    float acc = bihv;
    #pragma unroll 8
    for (int i = 0; i < 64; ++i) acc += xs[j][i] * b2f(ws[i * 256 + threadIdx.x]);
    gxE[(long)idx * 3072 + g0 + threadIdx.x] = f2b(acc);
  }
}

// ---------- bulk: decoder gx ----------
__global__ __launch_bounds__(256) void dec_gx_k(const float* __restrict__ inputs,
                                                const float* __restrict__ gWih,
                                                const float* __restrict__ gbias,
                                                unsigned short* __restrict__ gxD) {
  int g0 = blockIdx.x * 256;           // 8 slices of 256 (2048)
  int btg = blockIdx.y;
  __shared__ float ws[8][256];
  __shared__ float xs[64][8];
  for (int i = threadIdx.x; i < 8 * 256; i += 256)
    ws[i >> 8][i & 255] = gWih[(long)(i >> 8) * 2048 + g0 + (i & 255)];
  for (int i = threadIdx.x; i < 64 * 8; i += 256) {
    int idx = btg * 64 + (i >> 3);
    int t = idx >> 6, b = idx & 63;
    xs[i >> 3][i & 7] = inputs[((long)b * nT + t) * 8 + (i & 7)];
  }
  __syncthreads();
  float bv = gbias[g0 + threadIdx.x];
  for (int j = 0; j < 64; ++j) {
    int idx = btg * 64 + j;
    float acc = bv;
    #pragma unroll
    for (int i = 0; i < 8; ++i) acc += xs[j][i] * ws[i][threadIdx.x];
    gxD[(long)idx * 2048 + g0 + threadIdx.x] = f2b(acc);
  }
}

// ---------- bulk: x @ Wih_b per sample ----------
__global__ __launch_bounds__(256) void xW_k(const float* __restrict__ inputs,
                                            const float* __restrict__ Rest,
                                            unsigned short* __restrict__ xWb) {
  int k0 = blockIdx.x * 256;           // 4 slices of 256 (1024)
  int b = blockIdx.y;
  __shared__ float ws[8][256];
  __shared__ float xs[64][8];
  const float* RB = Rest + (long)b * REST_SZ + R_WIH;
  for (int i = threadIdx.x; i < 8 * 256; i += 256)
    ws[i >> 8][i & 255] = RB[(long)(i >> 8) * 1024 + k0 + (i & 255)];
  for (int i = threadIdx.x; i < 64 * 8; i += 256)
    xs[i >> 3][i & 7] = inputs[((long)b * nT + (i >> 3)) * 8 + (i & 7)];
  __syncthreads();
  for (int t = 0; t < 64; ++t) {
    float acc = 0.f;
    #pragma unroll
    for (int i = 0; i < 8; ++i) acc += xs[t][i] * ws[i][threadIdx.x];
    xWb[((long)t * 64 + b) * 1024 + k0 + threadIdx.x] = f2b(acc);
  }
}

// ---------- encoder fused step (round-4 structure, NCHE=16) ----------
__global__ __launch_bounds__(256) void enc_step_k(
    const unsigned short* __restrict__ W,       // [1024][3072] bf16 enc_Whh^T
    const unsigned short* __restrict__ gxE,     // [T][B][3072] bf16 (incl bih)
    const float* __restrict__ bhh,
    float* __restrict__ hEnc,                   // [B][1024] running h
    const float* __restrict__ pRr, const float* __restrict__ pZr, const float* __restrict__ pNr,
    float* __restrict__ pRw, float* __restrict__ pZw, float* __restrict__ pNw,
    int t) {
  int c = blockIdx.x & (NCHE - 1);
  int sp = blockIdx.x >> 4;
  int b0 = sp * 2, b1 = b0 + 1;
  __shared__ float h0s[CHRE], h1s[CHRE];

  // phase A: reduce previous partials + gates -> h(t) rows of chunk c
  int v = threadIdx.x;
  if (v < 2 * CHRE) {
    int hi = v >> 6;
    int bb = hi ? b1 : b0;
    int e = c * CHRE + (v & 63);
    float sr = 0.f, sz = 0.f, sn = 0.f;
    if (t > 0) {
      #pragma unroll
      for (int cc = 0; cc < NCHE; ++cc) {
        long base = ((long)cc * 64 + bb) * 1024 + e;
        sr += pRr[base]; sz += pZr[base]; sn += pNr[base];
      }
    }
    long gb = ((long)t * 64 + bb) * 3072;
    float xr = b2f(gxE[gb + e]), xz = b2f(gxE[gb + 1024 + e]), xn = b2f(gxE[gb + 2048 + e]);
    float hr = sr + bhh[e], hz = sz + bhh[1024 + e], hn = sn + bhh[2048 + e];
    float r = sigm(xr + hr);
    float z = sigm(xz + hz);
    float n = tanhf(xn + r * hn);
    float hold = (t > 0) ? hEnc[(long)bb * 1024 + e] : 0.f;
    float hnew = (1.f - z) * n + z * hold;
    hEnc[(long)bb * 1024 + e] = hnew;
    if (hi) h1s[v & 63] = hnew; else h0s[v & 63] = hnew;
  }
  __syncthreads();

  // phase B: partials for t+1
  if (t < nT - 1) {
    int e0 = threadIdx.x * 4;
    float ar0[4] = {}, az0[4] = {}, an0[4] = {}, ar1[4] = {}, az1[4] = {}, an1[4] = {};
    const unsigned short* Wb = W + (long)(c * CHRE) * 3072 + e0;
    #pragma unroll 4
    for (int j = 0; j < CHRE; ++j) {
      us4 wr = *(const us4*)(Wb + (long)j * 3072);
      us4 wz = *(const us4*)(Wb + (long)j * 3072 + 1024);
      us4 wn = *(const us4*)(Wb + (long)j * 3072 + 2048);
      float hv0 = h0s[j], hv1 = h1s[j];
      #pragma unroll
      for (int q = 0; q < 4; ++q) {
        float fr = b2f(wr[q]), fz = b2f(wz[q]), fn = b2f(wn[q]);
        ar0[q] += hv0 * fr; az0[q] += hv0 * fz; an0[q] += hv0 * fn;
        ar1[q] += hv1 * fr; az1[q] += hv1 * fz; an1[q] += hv1 * fn;
      }
    }
    long i0 = ((long)c * 64 + b0) * 1024 + e0;
    long i1 = i0 + 1024;
    *(float4*)(pRw + i0) = make_float4(ar0[0], ar0[1], ar0[2], ar0[3]);
    *(float4*)(pZw + i0) = make_float4(az0[0], az0[1], az0[2], az0[3]);
    *(float4*)(pNw + i0) = make_float4(an0[0], an0[1], an0[2], an0[3]);
    *(float4*)(pRw + i1) = make_float4(ar1[0], ar1[1], ar1[2], ar1[3]);
    *(float4*)(pZw + i1) = make_float4(az1[0], az1[1], az1[2], az1[3]);
    *(float4*)(pNw + i1) = make_float4(an1[0], an1[1], an1[2], an1[3]);
  }
}

// ---------- fused latent + hypernet layers 1-2 ----------
__global__ __launch_bounds__(256) void latent_hyper_k(
    const float* __restrict__ h_enc,
    const float* __restrict__ to_mu, const float* __restrict__ to_lsig,
    const float* __restrict__ lsig_bias, const float* __restrict__ eps,
    const float* __restrict__ W1, const float* __restrict__ b1,
    const float* __restrict__ W2, const float* __restrict__ b2,
    float* __restrict__ out_mu, float* __restrict__ out_lsig,
    float* __restrict__ a2out) {
  int b = blockIdx.x;
  __shared__ float hs[1024];
  __shared__ float zv[8];
  __shared__ float a1[1024];
  for (int i = threadIdx.x; i < 1024; i += 256) hs[i] = h_enc[b * 1024 + i];
  __syncthreads();
  int g = threadIdx.x >> 5, s = threadIdx.x & 31;
  if (g < nK) {
    float am = 0.f, as_ = 0.f;
    for (int h = s; h < 1024; h += 32) {
      float hv = hs[h];
      am += hv * to_mu[h * nK + g];
      as_ += hv * to_lsig[h * nK + g];
    }
    #pragma unroll
    for (int m = 16; m >= 1; m >>= 1) { am += __shfl_xor(am, m); as_ += __shfl_xor(as_, m); }
    if (s == 0) {
      float ls = as_ + lsig_bias[g];
      out_mu[b * nK + g] = am;
      out_lsig[b * nK + g] = ls;
      zv[g] = am + eps[b * nK + g] * __expf(ls);
    }
  }
  __syncthreads();
  for (int j = threadIdx.x; j < 1024; j += 256) {
    float acc = b1[j];
    #pragma unroll
    for (int i = 0; i < nK; ++i) acc += zv[i] * W1[i * 1024 + j];
    a1[j] = tanhf(acc);
  }
  __syncthreads();
  int l = threadIdx.x >> 3, s8 = threadIdx.x & 7;
  if (l < 30) {
    float acc = 0.f;
    for (int j = s8; j < 1024; j += 8) acc += a1[j] * W2[j * 30 + l];
    acc += __shfl_xor(acc, 4);
    acc += __shfl_xor(acc, 2);
    acc += __shfl_xor(acc, 1);
    if (s8 == 0) a2out[b * 30 + l] = acc + b2[l];
  }
}

// ---------- psi materialization: 2 outputs/thread, vectorized ----------
__global__ __launch_bounds__(256) void psi_k(const float* __restrict__ a2,
                                             const float* __restrict__ W3, const float* __restrict__ b3,
                                             unsigned short* __restrict__ WhhB, float* __restrict__ Rest) {
  __shared__ float sa[64 * 30];
  for (int i = threadIdx.x; i < 64 * 30; i += 256) sa[i] = a2[i];
  long n0 = ((long)blockIdx.x * 256 + threadIdx.x) * 2;
  __syncthreads();
  if (n0 >= N_PSI) return;
  float2 w[30];
  #pragma unroll
  for (int l = 0; l < 30; ++l) w[l] = *(const float2*)(W3 + (long)l * N_PSI + n0);
  float2 bb = *(const float2*)(b3 + n0);
  bool isWhh = (n0 < SZ_WHH);
  for (int b = 0; b < 64; ++b) {
    float a0 = bb.x, a1v = bb.y;
    const float* ab = &sa[b * 30];
    #pragma unroll
    for (int l = 0; l < 30; ++l) { float av = ab[l]; a0 += av * w[l].x; a1v += av * w[l].y; }
    if (isWhh) {
      us2 o; o[0] = f2b(a0); o[1] = f2b(a1v);
      *(us2*)(WhhB + (long)b * SZ_WHH + n0) = o;
    } else {
      *(float2*)(Rest + (long)b * REST_SZ + (n0 - SZ_WHH)) = make_float2(a0, a1v);
    }
  }
}

// ---------- decoder step v2: full-K GEMV blocks + shared-gates GEMM blocks ----------
// grid = 384: [0,256) GEMV (b, kq); [256,384) gates (8-sample group sg, 128-col tile gq)
__global__ __launch_bounds__(256) void dec_step2_k(
    const unsigned short* __restrict__ WhhB,   // [B][1024][1024] bf16
    const unsigned short* __restrict__ gWhhB,  // [1024][2048] bf16
    const unsigned short* __restrict__ gxD,    // [T][B][2048] bf16 (incl gbias)
    const unsigned short* __restrict__ xWb,    // [T][B][1024] bf16
    const float* __restrict__ Rest,
    float* __restrict__ decS,                  // [B][T][1024]
    const float* __restrict__ hWr, const float* __restrict__ preR,
    float* __restrict__ hWw, float* __restrict__ preW,
    int t) {
  int blk = blockIdx.x;
  int tid = threadIdx.x;
  if (blk < 256) {
    int b = blk >> 2, kq = blk & 3;
    __shared__ float hs[1024];
    __shared__ float part[4][64][4];
    // phase A: combine h(t) for sample b (all 1024 k); write decS quarter
    {
      int kk = tid * 4;
      float4 hold = make_float4(0.f, 0.f, 0.f, 0.f);
      if (t > 0) hold = *(const float4*)(decS + ((long)b * nT + (t - 1)) * 1024 + kk);
      const float* bh = Rest + (long)b * REST_SZ + R_BH;
      long gb = ((long)t * 64 + b) * 2048;
      long xb = ((long)t * 64 + b) * 1024;
      float hv[4]; float ho[4] = {hold.x, hold.y, hold.z, hold.w};
      #pragma unroll
      for (int q = 0; q < 4; ++q) {
        int k = kk + q;
        float pz = 0.f, pr = 0.f, hw = 0.f;
        if (t > 0) {
          pz = preR[(long)b * 2048 + k];
          pr = preR[(long)b * 2048 + 1024 + k];
          hw = hWr[(long)b * 1024 + k];
        }
        float z = sigm(b2f(gxD[gb + k]) + pz);
        float r = sigm(b2f(gxD[gb + 1024 + k]) + pr);
        float eta = tanhf(b2f(xWb[xb + k]) + r * tanhf(hw + bh[k]));
        hv[q] = z * ho[q] + (1.f - z) * eta;
      }
      *(float4*)(hs + kk) = make_float4(hv[0], hv[1], hv[2], hv[3]);
      if ((tid >> 6) == kq)
        *(float4*)(decS + ((long)b * nT + t) * 1024 + kk) = make_float4(hv[0], hv[1], hv[2], hv[3]);
    }
    __syncthreads();
    // phase B: full-K GEMV for 256 columns
    if (t < nT - 1) {
      int lane = tid & 63, hq = tid >> 6;
      int k0 = kq * 256 + lane * 4;
      const unsigned short* W = WhhB + (long)b * SZ_WHH + k0;
      float a0 = 0.f, a1 = 0.f, a2v = 0.f, a3 = 0.f;
      for (int h = hq; h < 1024; h += 4) {
        us4 w = *(const us4*)(W + (long)h * 1024);
        float hv = hs[h];
        a0 += hv * b2f(w[0]); a1 += hv * b2f(w[1]); a2v += hv * b2f(w[2]); a3 += hv * b2f(w[3]);
      }
      part[hq][lane][0] = a0; part[hq][lane][1] = a1; part[hq][lane][2] = a2v; part[hq][lane][3] = a3;
      __syncthreads();
      float s = part[0][tid >> 2][tid & 3] + part[1][tid >> 2][tid & 3]
              + part[2][tid >> 2][tid & 3] + part[3][tid >> 2][tid & 3];
      hWw[(long)b * 1024 + kq * 256 + tid] = s;
    }
  } else {
    int g = blk - 256;
    int sg = g >> 4, gq = g & 15;
    int s0 = sg * 8;
    __shared__ float hs8[8][1024];   // 32 KB
    for (int i = tid; i < 8192; i += 256) {
      int s = i >> 10, k = i & 1023;
      int b = s0 + s;
      float hold = (t > 0) ? decS[((long)b * nT + (t - 1)) * 1024 + k] : 0.f;
      float pz = 0.f, pr = 0.f, hw = 0.f;
      if (t > 0) {
        pz = preR[(long)b * 2048 + k];
        pr = preR[(long)b * 2048 + 1024 + k];
        hw = hWr[(long)b * 1024 + k];
      }
      long gb = ((long)t * 64 + b) * 2048;
      float z = sigm(b2f(gxD[gb + k]) + pz);
      float r = sigm(b2f(gxD[gb + 1024 + k]) + pr);
      float eta = tanhf(b2f(xWb[((long)t * 64 + b) * 1024 + k])
                        + r * tanhf(hw + Rest[(long)b * REST_SZ + R_BH + k]));
      hs8[s][k] = z * hold + (1.f - z) * eta;
    }
    __syncthreads();
    // phase B: shared gates GEMM tile: pre(t+1)[8 samples][128 cols]
    if (t < nT - 1) {
      int s = tid >> 5;
      int b = s0 + s;
      int cc = gq * 128 + (tid & 31) * 4;
      const unsigned short* G = gWhhB + cc;
      float a0 = 0.f, a1 = 0.f, a2v = 0.f, a3 = 0.f;
      for (int h = 0; h < 1024; ++h) {
        us4 w = *(const us4*)(G + (long)h * 2048);
        float hv = hs8[s][h];
        a0 += hv * b2f(w[0]); a1 += hv * b2f(w[1]); a2v += hv * b2f(w[2]); a3 += hv * b2f(w[3]);
      }
      *(float4*)(preW + (long)b * 2048 + cc) = make_float4(a0, a1, a2v, a3);
    }
  }
}

// ---------- readout: block = (sample, 8 timesteps), C stripe reused ----------
__global__ __launch_bounds__(256) void readout_k(
    const float* __restrict__ dec_seq, const float* __restrict__ inputs,
    const float* __restrict__ Rest, float* __restrict__ yhats) {
  int b = blockIdx.x >> 3;
  int tg = blockIdx.x & 7;
  __shared__ float ss[8][1024];
  __shared__ float part[4][8][64];
  for (int i = threadIdx.x; i < 8 * 1024; i += 256)
    ss[i >> 10][i & 1023] = dec_seq[((long)b * nT + tg * 8 + (i >> 10)) * 1024 + (i & 1023)];
  __syncthreads();
  int m = threadIdx.x & 63, hq = threadIdx.x >> 6;
  const float* C = Rest + (long)b * REST_SZ + R_C;
  float acc[8] = {};
  for (int h = hq * 256; h < hq * 256 + 256; ++h) {
    float cv = C[(long)h * 64 + m];
    #pragma unroll
    for (int tt = 0; tt < 8; ++tt) acc[tt] += ss[tt][h] * cv;
  }
  #pragma unroll
  for (int tt = 0; tt < 8; ++tt) part[hq][tt][m] = acc[tt];
  __syncthreads();
  const float* D = Rest + (long)b * REST_SZ + R_D;
  for (int o = threadIdx.x; o < 512; o += 256) {
    int tt = o >> 6, mm = o & 63;
    float a = part[0][tt][mm] + part[1][tt][mm] + part[2][tt][mm] + part[3][tt][mm];
    long bt = (long)b * nT + tg * 8 + tt;
    if (mm < 8) {
      a += inputs[bt * 8 + mm];
    } else {
      #pragma unroll
      for (int i = 0; i < 8; ++i) a += inputs[bt * 8 + i] * D[i * 56 + (mm - 8)];
    }
    yhats[bt * 64 + mm] = a;
  }
}

__global__ void copy_states_k(const float* __restrict__ dec_seq, float* __restrict__ states) {
  int i = blockIdx.x * 256 + threadIdx.x;
  int b = i >> 10, h = i & 1023;
  states[i] = dec_seq[((long)b * nT + (nT - 1)) * 1024 + h];
}

extern "C" void kernel_launch(void* const* d_in, const int* in_sizes, int n_in,
                              void* d_out, int out_size, void* d_ws, size_t ws_size,
                              hipStream_t stream) {
  const float* inputs  = (const float*)d_in[0];
  const float* outputs = (const float*)d_in[1];
  const float* eps     = (const float*)d_in[2];
  const float* enc_Wih = (const float*)d_in[3];
  const float* enc_Whh = (const float*)d_in[4];
  const float* enc_bih = (const float*)d_in[5];
  const float* enc_bhh = (const float*)d_in[6];
  const float* to_mu   = (const float*)d_in[7];
  const float* to_lsig = (const float*)d_in[8];
  const float* lsig_b  = (const float*)d_in[9];
  const float* W1 = (const float*)d_in[10];
  const float* b1 = (const float*)d_in[11];
  const float* W2 = (const float*)d_in[12];
  const float* b2 = (const float*)d_in[13];
  const float* W3 = (const float*)d_in[14];
  const float* b3 = (const float*)d_in[15];
  const float* gWih  = (const float*)d_in[16];
  const float* gWhh  = (const float*)d_in[17];
  const float* gbias = (const float*)d_in[18];

  char* ws = (char*)d_ws;
  size_t off = 0;
  auto alloc = [&](size_t bytes) { size_t o = off; off = (off + bytes + 255) & ~(size_t)255; return o; };
  size_t oWhhB   = alloc(64ull * SZ_WHH * 2);        // bf16 per-sample Whh
  size_t oRest   = alloc(64ull * REST_SZ * 4);       // fp32 psi remainder
  size_t ogWhhB  = alloc(1024ull * 2048 * 2);        // bf16 gru_Whh
  size_t oWtWhhB = alloc(1024ull * 3072 * 2);        // bf16 enc_Whh^T
  size_t oWtWihB = alloc(64ull * 3072 * 2);          // bf16 enc_Wih^T
  size_t ogxE    = alloc(64ull * 64 * 3072 * 2);     // bf16 encoder gx (incl bih)
  size_t ogxD    = alloc(64ull * 64 * 2048 * 2);     // bf16 decoder gx (incl gbias)
  size_t oxWb    = alloc(64ull * 64 * 1024 * 2);     // bf16 x@Wih_b
  size_t opA     = alloc((size_t)2 * PHALF_E * 4);   // encoder partials (dbuf)
  size_t opB     = alloc((size_t)2 * PHALF_E * 4);
  size_t opC     = alloc((size_t)2 * PHALF_E * 4);
  size_t ohA     = alloc(64ull * 1024 * 4);          // encoder running h
  size_t oHW     = alloc((size_t)2 * 64 * 1024 * 4); // decoder hW dbuf
  size_t oPre    = alloc((size_t)2 * 64 * 2048 * 4); // decoder pre dbuf
  size_t oDec    = alloc(64ull * 64 * 1024 * 4);
  size_t oA2     = alloc(64 * 30 * 4);
  (void)ws_size; (void)in_sizes; (void)n_in; (void)out_size;

  unsigned short* WhhB   = (unsigned short*)(ws + oWhhB);
  float*          Rest   = (float*)(ws + oRest);
  unsigned short* gWhhB  = (unsigned short*)(ws + ogWhhB);
  unsigned short* WtWhhB = (unsigned short*)(ws + oWtWhhB);
  unsigned short* WtWihB = (unsigned short*)(ws + oWtWihB);
  unsigned short* gxE    = (unsigned short*)(ws + ogxE);
  unsigned short* gxD    = (unsigned short*)(ws + ogxD);
  unsigned short* xWb    = (unsigned short*)(ws + oxWb);
  float* pA   = (float*)(ws + opA);
  float* pB   = (float*)(ws + opB);
  float* pC   = (float*)(ws + opC);
  float* hA   = (float*)(ws + ohA);
  float* hW   = (float*)(ws + oHW);
  float* pre  = (float*)(ws + oPre);
  float* decS = (float*)(ws + oDec);
  float* a2   = (float*)(ws + oA2);

  float* out    = (float*)d_out;
  float* out_yh = out;                 // 262144
  float* out_mu = out + 262144;        // 448
  float* out_ls = out + 262144 + 448;  // 448
  float* out_st = out + 262144 + 896;  // 65536

  // 1) weight preprocessing (bf16)
  transpose_bf16_k<<<dim3(32, 96), dim3(32, 8), 0, stream>>>(enc_Whh, WtWhhB, 3072, 1024);
  transpose_bf16_k<<<dim3(2, 96),  dim3(32, 8), 0, stream>>>(enc_Wih, WtWihB, 3072, 64);
  cvt_bf16_k<<<(int)((1024ull * 2048 + 255) / 256), 256, 0, stream>>>(gWhh, gWhhB, 1024 * 2048);

  // 2) bulk encoder gx
  enc_gx_k<<<dim3(12, 64), 256, 0, stream>>>(outputs, WtWihB, enc_bih, gxE);

  // 3) encoder recurrence (round-4 structure)
  for (int t = 0; t < nT; ++t) {
    int rp = t & 1, wp = (t + 1) & 1;
    enc_step_k<<<512, 256, 0, stream>>>(WtWhhB, gxE, enc_bhh, hA,
        pA + (size_t)rp * PHALF_E, pB + (size_t)rp * PHALF_E, pC + (size_t)rp * PHALF_E,
        pA + (size_t)wp * PHALF_E, pB + (size_t)wp * PHALF_E, pC + (size_t)wp * PHALF_E, t);
  }

  // 4) latent+hypernet fused, then psi
  latent_hyper_k<<<64, 256, 0, stream>>>(hA, to_mu, to_lsig, lsig_b, eps,
                                         W1, b1, W2, b2, out_mu, out_ls, a2);
  psi_k<<<(int)((N_PSI / 2 + 255) / 256), 256, 0, stream>>>(a2, W3, b3, WhhB, Rest);

  // 5) bulk decoder gx and x@Wih_b
  dec_gx_k<<<dim3(8, 64), 256, 0, stream>>>(inputs, gWih, gbias, gxD);
  xW_k<<<dim3(4, 64), 256, 0, stream>>>(inputs, Rest, xWb);

  // 6) decoder recurrence: one kernel per step, no partials
  for (int t = 0; t < nT; ++t) {
    int rp = t & 1, wp = (t + 1) & 1;
    dec_step2_k<<<384, 256, 0, stream>>>(WhhB, gWhhB, gxD, xWb, Rest, decS,
        hW + (size_t)rp * 65536, pre + (size_t)rp * 131072,
        hW + (size_t)wp * 65536, pre + (size_t)wp * 131072, t);
  }

  // 7) readout + states
  readout_k<<<512, 256, 0, stream>>>(decS, inputs, Rest, out_yh);
  copy_states_k<<<256, 256, 0, stream>>>(decS, out_st);
}

// Round 7
// 4448.817 us; speedup vs baseline: 1.7357x; 1.7357x over previous
//
#include <hip/hip_runtime.h>

// ---- problem constants ----
namespace {
constexpr int nT = 64;
constexpr int nK = 7;
constexpr long N_PSI = 1123776;
constexpr long SZ_WHH = 1048576;       // psi region 0: (1024,1024)
constexpr long REST_SZ = 75200;        // per-sample remaining psi elems
constexpr long R_BH = 0;               // (1024,)
constexpr long R_WIH = 1024;           // (8,1024)
constexpr long R_C = 9216;             // (1024,64)
constexpr long R_D = 74752;            // (8,56)
constexpr int NCHE = 16;               // h-chunks per step (enc + dec)
constexpr int CHRE = 64;               // rows per chunk
constexpr long PHALF_E = (long)NCHE * 64 * 1024;  // one partial buffer (floats)
}

typedef __attribute__((ext_vector_type(4))) unsigned short us4;
typedef __attribute__((ext_vector_type(2))) unsigned short us2;

__device__ __forceinline__ float b2f(unsigned short u) {
  return __uint_as_float(((unsigned int)u) << 16);
}
__device__ __forceinline__ unsigned short f2b(float f) {
  unsigned int u = __float_as_uint(f);
  return (unsigned short)((u + 0x7fffu + ((u >> 16) & 1u)) >> 16);
}
__device__ __forceinline__ float sigm(float x) { return 1.f / (1.f + __expf(-x)); }

// ---------- one-time: transpose (rows,cols) fp32 -> bf16 out[c*rows + r] ----------
__global__ void transpose_bf16_k(const float* __restrict__ in, unsigned short* __restrict__ out,
                                 int rows, int cols) {
  __shared__ float tile[32][33];
  int x = blockIdx.x * 32 + threadIdx.x;
  int y = blockIdx.y * 32 + threadIdx.y;
  #pragma unroll
  for (int i = 0; i < 32; i += 8)
    if ((y + i) < rows && x < cols) tile[threadIdx.y + i][threadIdx.x] = in[(long)(y + i) * cols + x];
  __syncthreads();
  x = blockIdx.y * 32 + threadIdx.x;
  y = blockIdx.x * 32 + threadIdx.y;
  #pragma unroll
  for (int i = 0; i < 32; i += 8)
    if ((y + i) < cols && x < rows) out[(long)(y + i) * rows + x] = f2b(tile[threadIdx.x][threadIdx.y + i]);
}

__global__ void cvt_bf16_k(const float* __restrict__ in, unsigned short* __restrict__ out, long n) {
  long i = (long)blockIdx.x * 256 + threadIdx.x;
  if (i < n) out[i] = f2b(in[i]);
}

// ---------- bulk: encoder gx ----------
__global__ __launch_bounds__(256) void enc_gx_k(const float* __restrict__ outputs,
                                                const unsigned short* __restrict__ WtWihB,
                                                const float* __restrict__ bih,
                                                unsigned short* __restrict__ gxE) {
  int g0 = blockIdx.x * 256;
  int btg = blockIdx.y;
  __shared__ unsigned short ws[64 * 256];
  __shared__ float xs[64][64];
  for (int i = threadIdx.x; i < 64 * 256; i += 256)
    ws[i] = WtWihB[(long)(i >> 8) * 3072 + g0 + (i & 255)];
  for (int i = threadIdx.x; i < 64 * 64; i += 256) {
    int idx = btg * 64 + (i >> 6);
    int t = idx >> 6, b = idx & 63;
    xs[i >> 6][i & 63] = outputs[((long)b * nT + t) * 64 + (i & 63)];
  }
  __syncthreads();
  float bihv = bih[g0 + threadIdx.x];
  for (int j = 0; j < 64; ++j) {
    int idx = btg * 64 + j;
    float acc = bihv;
    #pragma unroll 8
    for (int i = 0; i < 64; ++i) acc += xs[j][i] * b2f(ws[i * 256 + threadIdx.x]);
    gxE[(long)idx * 3072 + g0 + threadIdx.x] = f2b(acc);
  }
}

// ---------- bulk: decoder gx ----------
__global__ __launch_bounds__(256) void dec_gx_k(const float* __restrict__ inputs,
                                                const float* __restrict__ gWih,
                                                const float* __restrict__ gbias,
                                                unsigned short* __restrict__ gxD) {
  int g0 = blockIdx.x * 256;
  int btg = blockIdx.y;
  __shared__ float ws[8][256];
  __shared__ float xs[64][8];
  for (int i = threadIdx.x; i < 8 * 256; i += 256)
    ws[i >> 8][i & 255] = gWih[(long)(i >> 8) * 2048 + g0 + (i & 255)];
  for (int i = threadIdx.x; i < 64 * 8; i += 256) {
    int idx = btg * 64 + (i >> 3);
    int t = idx >> 6, b = idx & 63;
    xs[i >> 3][i & 7] = inputs[((long)b * nT + t) * 8 + (i & 7)];
  }
  __syncthreads();
  float bv = gbias[g0 + threadIdx.x];
  for (int j = 0; j < 64; ++j) {
    int idx = btg * 64 + j;
    float acc = bv;
    #pragma unroll
    for (int i = 0; i < 8; ++i) acc += xs[j][i] * ws[i][threadIdx.x];
    gxD[(long)idx * 2048 + g0 + threadIdx.x] = f2b(acc);
  }
}

// ---------- bulk: x @ Wih_b per sample ----------
__global__ __launch_bounds__(256) void xW_k(const float* __restrict__ inputs,
                                            const float* __restrict__ Rest,
                                            unsigned short* __restrict__ xWb) {
  int k0 = blockIdx.x * 256;
  int b = blockIdx.y;
  __shared__ float ws[8][256];
  __shared__ float xs[64][8];
  const float* RB = Rest + (long)b * REST_SZ + R_WIH;
  for (int i = threadIdx.x; i < 8 * 256; i += 256)
    ws[i >> 8][i & 255] = RB[(long)(i >> 8) * 1024 + k0 + (i & 255)];
  for (int i = threadIdx.x; i < 64 * 8; i += 256)
    xs[i >> 3][i & 7] = inputs[((long)b * nT + (i >> 3)) * 8 + (i & 7)];
  __syncthreads();
  for (int t = 0; t < 64; ++t) {
    float acc = 0.f;
    #pragma unroll
    for (int i = 0; i < 8; ++i) acc += xs[t][i] * ws[i][threadIdx.x];
    xWb[((long)t * 64 + b) * 1024 + k0 + threadIdx.x] = f2b(acc);
  }
}

// ---------- encoder fused step (round-4 structure, NCHE=16) ----------
__global__ __launch_bounds__(256) void enc_step_k(
    const unsigned short* __restrict__ W,       // [1024][3072] bf16 enc_Whh^T
    const unsigned short* __restrict__ gxE,     // [T][B][3072] bf16 (incl bih)
    const float* __restrict__ bhh,
    float* __restrict__ hEnc,                   // [B][1024] running h
    const float* __restrict__ pRr, const float* __restrict__ pZr, const float* __restrict__ pNr,
    float* __restrict__ pRw, float* __restrict__ pZw, float* __restrict__ pNw,
    int t) {
  int c = blockIdx.x & (NCHE - 1);
  int sp = blockIdx.x >> 4;
  int b0 = sp * 2, b1 = b0 + 1;
  __shared__ float h0s[CHRE], h1s[CHRE];

  int v = threadIdx.x;
  if (v < 2 * CHRE) {
    int hi = v >> 6;
    int bb = hi ? b1 : b0;
    int e = c * CHRE + (v & 63);
    float sr = 0.f, sz = 0.f, sn = 0.f;
    if (t > 0) {
      #pragma unroll
      for (int cc = 0; cc < NCHE; ++cc) {
        long base = ((long)cc * 64 + bb) * 1024 + e;
        sr += pRr[base]; sz += pZr[base]; sn += pNr[base];
      }
    }
    long gb = ((long)t * 64 + bb) * 3072;
    float xr = b2f(gxE[gb + e]), xz = b2f(gxE[gb + 1024 + e]), xn = b2f(gxE[gb + 2048 + e]);
    float hr = sr + bhh[e], hz = sz + bhh[1024 + e], hn = sn + bhh[2048 + e];
    float r = sigm(xr + hr);
    float z = sigm(xz + hz);
    float n = tanhf(xn + r * hn);
    float hold = (t > 0) ? hEnc[(long)bb * 1024 + e] : 0.f;
    float hnew = (1.f - z) * n + z * hold;
    hEnc[(long)bb * 1024 + e] = hnew;
    if (hi) h1s[v & 63] = hnew; else h0s[v & 63] = hnew;
  }
  __syncthreads();

  if (t < nT - 1) {
    int e0 = threadIdx.x * 4;
    float ar0[4] = {}, az0[4] = {}, an0[4] = {}, ar1[4] = {}, az1[4] = {}, an1[4] = {};
    const unsigned short* Wb = W + (long)(c * CHRE) * 3072 + e0;
    #pragma unroll 4
    for (int j = 0; j < CHRE; ++j) {
      us4 wr = *(const us4*)(Wb + (long)j * 3072);
      us4 wz = *(const us4*)(Wb + (long)j * 3072 + 1024);
      us4 wn = *(const us4*)(Wb + (long)j * 3072 + 2048);
      float hv0 = h0s[j], hv1 = h1s[j];
      #pragma unroll
      for (int q = 0; q < 4; ++q) {
        float fr = b2f(wr[q]), fz = b2f(wz[q]), fn = b2f(wn[q]);
        ar0[q] += hv0 * fr; az0[q] += hv0 * fz; an0[q] += hv0 * fn;
        ar1[q] += hv1 * fr; az1[q] += hv1 * fz; an1[q] += hv1 * fn;
      }
    }
    long i0 = ((long)c * 64 + b0) * 1024 + e0;
    long i1 = i0 + 1024;
    *(float4*)(pRw + i0) = make_float4(ar0[0], ar0[1], ar0[2], ar0[3]);
    *(float4*)(pZw + i0) = make_float4(az0[0], az0[1], az0[2], az0[3]);
    *(float4*)(pNw + i0) = make_float4(an0[0], an0[1], an0[2], an0[3]);
    *(float4*)(pRw + i1) = make_float4(ar1[0], ar1[1], ar1[2], ar1[3]);
    *(float4*)(pZw + i1) = make_float4(az1[0], az1[1], az1[2], az1[3]);
    *(float4*)(pNw + i1) = make_float4(an1[0], an1[1], an1[2], an1[3]);
  }
}

// ---------- fused latent + hypernet layers 1-2 ----------
__global__ __launch_bounds__(256) void latent_hyper_k(
    const float* __restrict__ h_enc,
    const float* __restrict__ to_mu, const float* __restrict__ to_lsig,
    const float* __restrict__ lsig_bias, const float* __restrict__ eps,
    const float* __restrict__ W1, const float* __restrict__ b1,
    const float* __restrict__ W2, const float* __restrict__ b2,
    float* __restrict__ out_mu, float* __restrict__ out_lsig,
    float* __restrict__ a2out) {
  int b = blockIdx.x;
  __shared__ float hs[1024];
  __shared__ float zv[8];
  __shared__ float a1[1024];
  for (int i = threadIdx.x; i < 1024; i += 256) hs[i] = h_enc[b * 1024 + i];
  __syncthreads();
  int g = threadIdx.x >> 5, s = threadIdx.x & 31;
  if (g < nK) {
    float am = 0.f, as_ = 0.f;
    for (int h = s; h < 1024; h += 32) {
      float hv = hs[h];
      am += hv * to_mu[h * nK + g];
      as_ += hv * to_lsig[h * nK + g];
    }
    #pragma unroll
    for (int m = 16; m >= 1; m >>= 1) { am += __shfl_xor(am, m); as_ += __shfl_xor(as_, m); }
    if (s == 0) {
      float ls = as_ + lsig_bias[g];
      out_mu[b * nK + g] = am;
      out_lsig[b * nK + g] = ls;
      zv[g] = am + eps[b * nK + g] * __expf(ls);
    }
  }
  __syncthreads();
  for (int j = threadIdx.x; j < 1024; j += 256) {
    float acc = b1[j];
    #pragma unroll
    for (int i = 0; i < nK; ++i) acc += zv[i] * W1[i * 1024 + j];
    a1[j] = tanhf(acc);
  }
  __syncthreads();
  int l = threadIdx.x >> 3, s8 = threadIdx.x & 7;
  if (l < 30) {
    float acc = 0.f;
    for (int j = s8; j < 1024; j += 8) acc += a1[j] * W2[j * 30 + l];
    acc += __shfl_xor(acc, 4);
    acc += __shfl_xor(acc, 2);
    acc += __shfl_xor(acc, 1);
    if (s8 == 0) a2out[b * 30 + l] = acc + b2[l];
  }
}

// ---------- psi materialization: 2 outputs/thread, vectorized ----------
__global__ __launch_bounds__(256) void psi_k(const float* __restrict__ a2,
                                             const float* __restrict__ W3, const float* __restrict__ b3,
                                             unsigned short* __restrict__ WhhB, float* __restrict__ Rest) {
  __shared__ float sa[64 * 30];
  for (int i = threadIdx.x; i < 64 * 30; i += 256) sa[i] = a2[i];
  long n0 = ((long)blockIdx.x * 256 + threadIdx.x) * 2;
  __syncthreads();
  if (n0 >= N_PSI) return;
  float2 w[30];
  #pragma unroll
  for (int l = 0; l < 30; ++l) w[l] = *(const float2*)(W3 + (long)l * N_PSI + n0);
  float2 bb = *(const float2*)(b3 + n0);
  bool isWhh = (n0 < SZ_WHH);
  for (int b = 0; b < 64; ++b) {
    float a0 = bb.x, a1v = bb.y;
    const float* ab = &sa[b * 30];
    #pragma unroll
    for (int l = 0; l < 30; ++l) { float av = ab[l]; a0 += av * w[l].x; a1v += av * w[l].y; }
    if (isWhh) {
      us2 o; o[0] = f2b(a0); o[1] = f2b(a1v);
      *(us2*)(WhhB + (long)b * SZ_WHH + n0) = o;
    } else {
      *(float2*)(Rest + (long)b * REST_SZ + (n0 - SZ_WHH)) = make_float2(a0, a1v);
    }
  }
}

// ---------- decoder step v3: role-split, chunked partials ----------
// grid = 1152: [0,1024) GEMV blocks (c = blk>>6, b = blk&63) -> pW partials + h/decS write
//              [1024,1152) gate blocks (g = blk-1024: c = g>>3, sg = g&7) -> pGz/pGr partials
__global__ __launch_bounds__(256) void dec_step3_k(
    const unsigned short* __restrict__ WhhB,   // [B][1024][1024] bf16
    const unsigned short* __restrict__ gWhhB,  // [1024][2048] bf16
    const unsigned short* __restrict__ gxD,    // [T][B][2048] bf16 (incl gbias)
    const unsigned short* __restrict__ xWb,    // [T][B][1024] bf16
    const float* __restrict__ Rest,
    float* __restrict__ decS,                  // [B][T][1024]
    const float* __restrict__ pWr, const float* __restrict__ pGzr, const float* __restrict__ pGrr,
    float* __restrict__ pWw, float* __restrict__ pGzw, float* __restrict__ pGrw,
    int t) {
  int tid = threadIdx.x;
  if (blockIdx.x < 1024) {
    int c = blockIdx.x >> 6, b = blockIdx.x & 63;
    __shared__ float hs[64];
    __shared__ float red[3][64][4];
    // phase A: 4-way parallel reduce of partials for this chunk's 64 rows
    {
      int row = tid >> 2, p = tid & 3;
      int e = c * 64 + row;
      float sw = 0.f, sz = 0.f, sr = 0.f;
      if (t > 0) {
        #pragma unroll
        for (int cc = p * 4; cc < p * 4 + 4; ++cc) {
          long base = ((long)cc * 64 + b) * 1024 + e;
          sw += pWr[base]; sz += pGzr[base]; sr += pGrr[base];
        }
      }
      red[0][row][p] = sw; red[1][row][p] = sz; red[2][row][p] = sr;
    }
    __syncthreads();
    if (tid < 64) {
      int e = c * 64 + tid;
      float sw = red[0][tid][0] + red[0][tid][1] + red[0][tid][2] + red[0][tid][3];
      float sz = red[1][tid][0] + red[1][tid][1] + red[1][tid][2] + red[1][tid][3];
      float sr = red[2][tid][0] + red[2][tid][1] + red[2][tid][2] + red[2][tid][3];
      long gb = ((long)t * 64 + b) * 2048;
      float z = sigm(b2f(gxD[gb + e]) + sz);
      float r = sigm(b2f(gxD[gb + 1024 + e]) + sr);
      float hW_ = sw + Rest[(long)b * REST_SZ + R_BH + e];
      float xw = b2f(xWb[((long)t * 64 + b) * 1024 + e]);
      float eta = tanhf(xw + r * tanhf(hW_));
      float hold = (t > 0) ? decS[((long)b * nT + (t - 1)) * 1024 + e] : 0.f;
      float hn = z * hold + (1.f - z) * eta;
      decS[((long)b * nT + t) * 1024 + e] = hn;
      hs[tid] = hn;
    }
    __syncthreads();
    // phase B: pW partial = h_chunk @ Whh_b[chunk rows, all 1024 cols]
    if (t < nT - 1) {
      int k0 = tid * 4;
      const unsigned short* W = WhhB + (long)b * SZ_WHH + (long)(c * 64) * 1024 + k0;
      float a0 = 0.f, a1 = 0.f, a2v = 0.f, a3 = 0.f;
      #pragma unroll 4
      for (int j = 0; j < 64; ++j) {
        us4 w = *(const us4*)(W + (long)j * 1024);
        float hv = hs[j];
        a0 += hv * b2f(w[0]); a1 += hv * b2f(w[1]); a2v += hv * b2f(w[2]); a3 += hv * b2f(w[3]);
      }
      *(float4*)(pWw + ((long)c * 64 + b) * 1024 + k0) = make_float4(a0, a1, a2v, a3);
    }
  } else {
    int g = blockIdx.x - 1024;
    int c = g >> 3, sg = g & 7, s0 = sg * 8;
    __shared__ float h8[8][64];
    // phase A: recompute h(t) chunk-c rows for 8 samples
    #pragma unroll
    for (int pass = 0; pass < 2; ++pass) {
      int idx = pass * 256 + tid;          // 0..511
      int s = idx >> 6, row = idx & 63;
      int b = s0 + s, e = c * 64 + row;
      float sw = 0.f, sz = 0.f, sr = 0.f;
      if (t > 0) {
        #pragma unroll 4
        for (int cc = 0; cc < 16; ++cc) {
          long base = ((long)cc * 64 + b) * 1024 + e;
          sw += pWr[base]; sz += pGzr[base]; sr += pGrr[base];
        }
      }
      long gb = ((long)t * 64 + b) * 2048;
      float z = sigm(b2f(gxD[gb + e]) + sz);
      float r = sigm(b2f(gxD[gb + 1024 + e]) + sr);
      float eta = tanhf(b2f(xWb[((long)t * 64 + b) * 1024 + e])
                        + r * tanhf(sw + Rest[(long)b * REST_SZ + R_BH + e]));
      float hold = (t > 0) ? decS[((long)b * nT + (t - 1)) * 1024 + e] : 0.f;
      h8[s][row] = z * hold + (1.f - z) * eta;
    }
    __syncthreads();
    // phase B: pGz/pGr partials for 8 samples (gWhh stripe read once per block)
    if (t < nT - 1) {
      int k0 = tid * 4;
      const unsigned short* G = gWhhB + (long)(c * 64) * 2048 + k0;
      float az[8][4] = {}; float ar[8][4] = {};
      #pragma unroll 2
      for (int j = 0; j < 64; ++j) {
        us4 wz = *(const us4*)(G + (long)j * 2048);
        us4 wr = *(const us4*)(G + (long)j * 2048 + 1024);
        float fz[4], fr[4];
        #pragma unroll
        for (int q = 0; q < 4; ++q) { fz[q] = b2f(wz[q]); fr[q] = b2f(wr[q]); }
        #pragma unroll
        for (int s = 0; s < 8; ++s) {
          float hv = h8[s][j];
          #pragma unroll
          for (int q = 0; q < 4; ++q) { az[s][q] += hv * fz[q]; ar[s][q] += hv * fr[q]; }
        }
      }
      #pragma unroll
      for (int s = 0; s < 8; ++s) {
        *(float4*)(pGzw + ((long)c * 64 + s0 + s) * 1024 + k0) = make_float4(az[s][0], az[s][1], az[s][2], az[s][3]);
        *(float4*)(pGrw + ((long)c * 64 + s0 + s) * 1024 + k0) = make_float4(ar[s][0], ar[s][1], ar[s][2], ar[s][3]);
      }
    }
  }
}

// ---------- readout: block = (sample, 8 timesteps), C stripe reused ----------
__global__ __launch_bounds__(256) void readout_k(
    const float* __restrict__ dec_seq, const float* __restrict__ inputs,
    const float* __restrict__ Rest, float* __restrict__ yhats) {
  int b = blockIdx.x >> 3;
  int tg = blockIdx.x & 7;
  __shared__ float ss[8][1024];
  __shared__ float part[4][8][64];
  for (int i = threadIdx.x; i < 8 * 1024; i += 256)
    ss[i >> 10][i & 1023] = dec_seq[((long)b * nT + tg * 8 + (i >> 10)) * 1024 + (i & 1023)];
  __syncthreads();
  int m = threadIdx.x & 63, hq = threadIdx.x >> 6;
  const float* C = Rest + (long)b * REST_SZ + R_C;
  float acc[8] = {};
  for (int h = hq * 256; h < hq * 256 + 256; ++h) {
    float cv = C[(long)h * 64 + m];
    #pragma unroll
    for (int tt = 0; tt < 8; ++tt) acc[tt] += ss[tt][h] * cv;
  }
  #pragma unroll
  for (int tt = 0; tt < 8; ++tt) part[hq][tt][m] = acc[tt];
  __syncthreads();
  const float* D = Rest + (long)b * REST_SZ + R_D;
  for (int o = threadIdx.x; o < 512; o += 256) {
    int tt = o >> 6, mm = o & 63;
    float a = part[0][tt][mm] + part[1][tt][mm] + part[2][tt][mm] + part[3][tt][mm];
    long bt = (long)b * nT + tg * 8 + tt;
    if (mm < 8) {
      a += inputs[bt * 8 + mm];
    } else {
      #pragma unroll
      for (int i = 0; i < 8; ++i) a += inputs[bt * 8 + i] * D[i * 56 + (mm - 8)];
    }
    yhats[bt * 64 + mm] = a;
  }
}

__global__ void copy_states_k(const float* __restrict__ dec_seq, float* __restrict__ states) {
  int i = blockIdx.x * 256 + threadIdx.x;
  int b = i >> 10, h = i & 1023;
  states[i] = dec_seq[((long)b * nT + (nT - 1)) * 1024 + h];
}

extern "C" void kernel_launch(void* const* d_in, const int* in_sizes, int n_in,
                              void* d_out, int out_size, void* d_ws, size_t ws_size,
                              hipStream_t stream) {
  const float* inputs  = (const float*)d_in[0];
  const float* outputs = (const float*)d_in[1];
  const float* eps     = (const float*)d_in[2];
  const float* enc_Wih = (const float*)d_in[3];
  const float* enc_Whh = (const float*)d_in[4];
  const float* enc_bih = (const float*)d_in[5];
  const float* enc_bhh = (const float*)d_in[6];
  const float* to_mu   = (const float*)d_in[7];
  const float* to_lsig = (const float*)d_in[8];
  const float* lsig_b  = (const float*)d_in[9];
  const float* W1 = (const float*)d_in[10];
  const float* b1 = (const float*)d_in[11];
  const float* W2 = (const float*)d_in[12];
  const float* b2 = (const float*)d_in[13];
  const float* W3 = (const float*)d_in[14];
  const float* b3 = (const float*)d_in[15];
  const float* gWih  = (const float*)d_in[16];
  const float* gWhh  = (const float*)d_in[17];
  const float* gbias = (const float*)d_in[18];

  char* ws = (char*)d_ws;
  size_t off = 0;
  auto alloc = [&](size_t bytes) { size_t o = off; off = (off + bytes + 255) & ~(size_t)255; return o; };
  size_t oWhhB   = alloc(64ull * SZ_WHH * 2);        // bf16 per-sample Whh
  size_t oRest   = alloc(64ull * REST_SZ * 4);       // fp32 psi remainder
  size_t ogWhhB  = alloc(1024ull * 2048 * 2);        // bf16 gru_Whh
  size_t oWtWhhB = alloc(1024ull * 3072 * 2);        // bf16 enc_Whh^T
  size_t oWtWihB = alloc(64ull * 3072 * 2);          // bf16 enc_Wih^T
  size_t ogxE    = alloc(64ull * 64 * 3072 * 2);     // bf16 encoder gx (incl bih)
  size_t ogxD    = alloc(64ull * 64 * 2048 * 2);     // bf16 decoder gx (incl gbias)
  size_t oxWb    = alloc(64ull * 64 * 1024 * 2);     // bf16 x@Wih_b
  size_t opA     = alloc((size_t)2 * PHALF_E * 4);   // dbuf partials (enc R / dec W)
  size_t opB     = alloc((size_t)2 * PHALF_E * 4);   // dbuf partials (enc Z / dec Gz)
  size_t opC     = alloc((size_t)2 * PHALF_E * 4);   // dbuf partials (enc N / dec Gr)
  size_t ohA     = alloc(64ull * 1024 * 4);          // encoder running h
  size_t oDec    = alloc(64ull * 64 * 1024 * 4);
  size_t oA2     = alloc(64 * 30 * 4);
  (void)ws_size; (void)in_sizes; (void)n_in; (void)out_size;

  unsigned short* WhhB   = (unsigned short*)(ws + oWhhB);
  float*          Rest   = (float*)(ws + oRest);
  unsigned short* gWhhB  = (unsigned short*)(ws + ogWhhB);
  unsigned short* WtWhhB = (unsigned short*)(ws + oWtWhhB);
  unsigned short* WtWihB = (unsigned short*)(ws + oWtWihB);
  unsigned short* gxE    = (unsigned short*)(ws + ogxE);
  unsigned short* gxD    = (unsigned short*)(ws + ogxD);
  unsigned short* xWb    = (unsigned short*)(ws + oxWb);
  float* pA   = (float*)(ws + opA);
  float* pB   = (float*)(ws + opB);
  float* pC   = (float*)(ws + opC);
  float* hA   = (float*)(ws + ohA);
  float* decS = (float*)(ws + oDec);
  float* a2   = (float*)(ws + oA2);

  float* out    = (float*)d_out;
  float* out_yh = out;                 // 262144
  float* out_mu = out + 262144;        // 448
  float* out_ls = out + 262144 + 448;  // 448
  float* out_st = out + 262144 + 896;  // 65536

  // 1) weight preprocessing (bf16)
  transpose_bf16_k<<<dim3(32, 96), dim3(32, 8), 0, stream>>>(enc_Whh, WtWhhB, 3072, 1024);
  transpose_bf16_k<<<dim3(2, 96),  dim3(32, 8), 0, stream>>>(enc_Wih, WtWihB, 3072, 64);
  cvt_bf16_k<<<(int)((1024ull * 2048 + 255) / 256), 256, 0, stream>>>(gWhh, gWhhB, 1024 * 2048);

  // 2) bulk encoder gx
  enc_gx_k<<<dim3(12, 64), 256, 0, stream>>>(outputs, WtWihB, enc_bih, gxE);

  // 3) encoder recurrence (round-4 structure)
  for (int t = 0; t < nT; ++t) {
    int rp = t & 1, wp = (t + 1) & 1;
    enc_step_k<<<512, 256, 0, stream>>>(WtWhhB, gxE, enc_bhh, hA,
        pA + (size_t)rp * PHALF_E, pB + (size_t)rp * PHALF_E, pC + (size_t)rp * PHALF_E,
        pA + (size_t)wp * PHALF_E, pB + (size_t)wp * PHALF_E, pC + (size_t)wp * PHALF_E, t);
  }

  // 4) latent+hypernet fused, then psi
  latent_hyper_k<<<64, 256, 0, stream>>>(hA, to_mu, to_lsig, lsig_b, eps,
                                         W1, b1, W2, b2, out_mu, out_ls, a2);
  psi_k<<<(int)((N_PSI / 2 + 255) / 256), 256, 0, stream>>>(a2, W3, b3, WhhB, Rest);

  // 5) bulk decoder gx and x@Wih_b
  dec_gx_k<<<dim3(8, 64), 256, 0, stream>>>(inputs, gWih, gbias, gxD);
  xW_k<<<dim3(4, 64), 256, 0, stream>>>(inputs, Rest, xWb);

  // 6) decoder recurrence: role-split single kernel per step
  for (int t = 0; t < nT; ++t) {
    int rp = t & 1, wp = (t + 1) & 1;
    dec_step3_k<<<1152, 256, 0, stream>>>(WhhB, gWhhB, gxD, xWb, Rest, decS,
        pA + (size_t)rp * PHALF_E, pB + (size_t)rp * PHALF_E, pC + (size_t)rp * PHALF_E,
        pA + (size_t)wp * PHALF_E, pB + (size_t)wp * PHALF_E, pC + (size_t)wp * PHALF_E, t);
  }

  // 7) readout + states
  readout_k<<<512, 256, 0, stream>>>(decS, inputs, Rest, out_yh);
  copy_states_k<<<256, 256, 0, stream>>>(decS, out_st);
}

// Round 8
// 2989.106 us; speedup vs baseline: 2.5833x; 1.4883x over previous
//
#include <hip/hip_runtime.h>

// ---- problem constants ----
namespace {
constexpr int nT = 64;
constexpr int nK = 7;
constexpr long N_PSI = 1123776;
constexpr long SZ_WHH = 1048576;       // psi region 0: (1024,1024)
constexpr long REST_SZ = 75200;        // per-sample remaining psi elems
constexpr long R_BH = 0;               // (1024,)
constexpr long R_WIH = 1024;           // (8,1024)
constexpr long R_C = 9216;             // (1024,64)
constexpr long R_D = 74752;            // (8,56)
constexpr int NCH = 16;                // h-chunks per step
constexpr int CHR = 64;                // rows per chunk
constexpr long PHALF = (long)NCH * 64 * 1024;  // one partial buffer (floats)
}

typedef __attribute__((ext_vector_type(4))) unsigned short us4;
typedef __attribute__((ext_vector_type(2))) unsigned short us2;

__device__ __forceinline__ float b2f(unsigned short u) {
  return __uint_as_float(((unsigned int)u) << 16);
}
__device__ __forceinline__ unsigned short f2b(float f) {
  unsigned int u = __float_as_uint(f);
  return (unsigned short)((u + 0x7fffu + ((u >> 16) & 1u)) >> 16);
}
__device__ __forceinline__ float sigm(float x) { return 1.f / (1.f + __expf(-x)); }

// ---------- one-time: transpose (rows,cols) fp32 -> bf16 out[c*rows + r] ----------
__global__ void transpose_bf16_k(const float* __restrict__ in, unsigned short* __restrict__ out,
                                 int rows, int cols) {
  __shared__ float tile[32][33];
  int x = blockIdx.x * 32 + threadIdx.x;
  int y = blockIdx.y * 32 + threadIdx.y;
  #pragma unroll
  for (int i = 0; i < 32; i += 8)
    if ((y + i) < rows && x < cols) tile[threadIdx.y + i][threadIdx.x] = in[(long)(y + i) * cols + x];
  __syncthreads();
  x = blockIdx.y * 32 + threadIdx.x;
  y = blockIdx.x * 32 + threadIdx.y;
  #pragma unroll
  for (int i = 0; i < 32; i += 8)
    if ((y + i) < cols && x < rows) out[(long)(y + i) * rows + x] = f2b(tile[threadIdx.x][threadIdx.y + i]);
}

__global__ void cvt_bf16_k(const float* __restrict__ in, unsigned short* __restrict__ out, long n) {
  long i = (long)blockIdx.x * 256 + threadIdx.x;
  if (i < n) out[i] = f2b(in[i]);
}

// ---------- bulk: encoder gx ----------
__global__ __launch_bounds__(256) void enc_gx_k(const float* __restrict__ outputs,
                                                const unsigned short* __restrict__ WtWihB,
                                                const float* __restrict__ bih,
                                                unsigned short* __restrict__ gxE) {
  int g0 = blockIdx.x * 256;
  int btg = blockIdx.y;
  __shared__ unsigned short ws[64 * 256];
  __shared__ float xs[64][64];
  for (int i = threadIdx.x; i < 64 * 256; i += 256)
    ws[i] = WtWihB[(long)(i >> 8) * 3072 + g0 + (i & 255)];
  for (int i = threadIdx.x; i < 64 * 64; i += 256) {
    int idx = btg * 64 + (i >> 6);
    int t = idx >> 6, b = idx & 63;
    xs[i >> 6][i & 63] = outputs[((long)b * nT + t) * 64 + (i & 63)];
  }
  __syncthreads();
  float bihv = bih[g0 + threadIdx.x];
  for (int j = 0; j < 64; ++j) {
    int idx = btg * 64 + j;
    float acc = bihv;
    #pragma unroll 8
    for (int i = 0; i < 64; ++i) acc += xs[j][i] * b2f(ws[i * 256 + threadIdx.x]);
    gxE[(long)idx * 3072 + g0 + threadIdx.x] = f2b(acc);
  }
}

// ---------- bulk: decoder gx ----------
__global__ __launch_bounds__(256) void dec_gx_k(const float* __restrict__ inputs,
                                                const float* __restrict__ gWih,
                                                const float* __restrict__ gbias,
                                                unsigned short* __restrict__ gxD) {
  int g0 = blockIdx.x * 256;
  int btg = blockIdx.y;
  __shared__ float ws[8][256];
  __shared__ float xs[64][8];
  for (int i = threadIdx.x; i < 8 * 256; i += 256)
    ws[i >> 8][i & 255] = gWih[(long)(i >> 8) * 2048 + g0 + (i & 255)];
  for (int i = threadIdx.x; i < 64 * 8; i += 256) {
    int idx = btg * 64 + (i >> 3);
    int t = idx >> 6, b = idx & 63;
    xs[i >> 3][i & 7] = inputs[((long)b * nT + t) * 8 + (i & 7)];
  }
  __syncthreads();
  float bv = gbias[g0 + threadIdx.x];
  for (int j = 0; j < 64; ++j) {
    int idx = btg * 64 + j;
    float acc = bv;
    #pragma unroll
    for (int i = 0; i < 8; ++i) acc += xs[j][i] * ws[i][threadIdx.x];
    gxD[(long)idx * 2048 + g0 + threadIdx.x] = f2b(acc);
  }
}

// ---------- bulk: x @ Wih_b per sample ----------
__global__ __launch_bounds__(256) void xW_k(const float* __restrict__ inputs,
                                            const float* __restrict__ Rest,
                                            unsigned short* __restrict__ xWb) {
  int k0 = blockIdx.x * 256;
  int b = blockIdx.y;
  __shared__ float ws[8][256];
  __shared__ float xs[64][8];
  const float* RB = Rest + (long)b * REST_SZ + R_WIH;
  for (int i = threadIdx.x; i < 8 * 256; i += 256)
    ws[i >> 8][i & 255] = RB[(long)(i >> 8) * 1024 + k0 + (i & 255)];
  for (int i = threadIdx.x; i < 64 * 8; i += 256)
    xs[i >> 3][i & 7] = inputs[((long)b * nT + (i >> 3)) * 8 + (i & 7)];
  __syncthreads();
  for (int t = 0; t < 64; ++t) {
    float acc = 0.f;
    #pragma unroll
    for (int i = 0; i < 8; ++i) acc += xs[t][i] * ws[i][threadIdx.x];
    xWb[((long)t * 64 + b) * 1024 + k0 + threadIdx.x] = f2b(acc);
  }
}

// ---------- encoder fused step (r4 structure) ----------
__global__ __launch_bounds__(256) void enc_step_k(
    const unsigned short* __restrict__ W,       // [1024][3072] bf16 enc_Whh^T
    const unsigned short* __restrict__ gxE,     // [T][B][3072] bf16 (incl bih)
    const float* __restrict__ bhh,
    float* __restrict__ hEnc,                   // [B][1024] running h
    const float* __restrict__ pRr, const float* __restrict__ pZr, const float* __restrict__ pNr,
    float* __restrict__ pRw, float* __restrict__ pZw, float* __restrict__ pNw,
    int t) {
  int c = blockIdx.x & (NCH - 1);
  int sp = blockIdx.x >> 4;
  int b0 = sp * 2, b1 = b0 + 1;
  __shared__ float h0s[CHR], h1s[CHR];

  int v = threadIdx.x;
  if (v < 2 * CHR) {
    int hi = v >> 6;
    int bb = hi ? b1 : b0;
    int e = c * CHR + (v & 63);
    float sr = 0.f, sz = 0.f, sn = 0.f;
    if (t > 0) {
      #pragma unroll
      for (int cc = 0; cc < NCH; ++cc) {
        long base = ((long)cc * 64 + bb) * 1024 + e;
        sr += pRr[base]; sz += pZr[base]; sn += pNr[base];
      }
    }
    long gb = ((long)t * 64 + bb) * 3072;
    float xr = b2f(gxE[gb + e]), xz = b2f(gxE[gb + 1024 + e]), xn = b2f(gxE[gb + 2048 + e]);
    float hr = sr + bhh[e], hz = sz + bhh[1024 + e], hn = sn + bhh[2048 + e];
    float r = sigm(xr + hr);
    float z = sigm(xz + hz);
    float n = tanhf(xn + r * hn);
    float hold = (t > 0) ? hEnc[(long)bb * 1024 + e] : 0.f;
    float hnew = (1.f - z) * n + z * hold;
    hEnc[(long)bb * 1024 + e] = hnew;
    if (hi) h1s[v & 63] = hnew; else h0s[v & 63] = hnew;
  }
  __syncthreads();

  if (t < nT - 1) {
    int e0 = threadIdx.x * 4;
    float ar0[4] = {}, az0[4] = {}, an0[4] = {}, ar1[4] = {}, az1[4] = {}, an1[4] = {};
    const unsigned short* Wb = W + (long)(c * CHR) * 3072 + e0;
    #pragma unroll 4
    for (int j = 0; j < CHR; ++j) {
      us4 wr = *(const us4*)(Wb + (long)j * 3072);
      us4 wz = *(const us4*)(Wb + (long)j * 3072 + 1024);
      us4 wn = *(const us4*)(Wb + (long)j * 3072 + 2048);
      float hv0 = h0s[j], hv1 = h1s[j];
      #pragma unroll
      for (int q = 0; q < 4; ++q) {
        float fr = b2f(wr[q]), fz = b2f(wz[q]), fn = b2f(wn[q]);
        ar0[q] += hv0 * fr; az0[q] += hv0 * fz; an0[q] += hv0 * fn;
        ar1[q] += hv1 * fr; az1[q] += hv1 * fz; an1[q] += hv1 * fn;
      }
    }
    long i0 = ((long)c * 64 + b0) * 1024 + e0;
    long i1 = i0 + 1024;
    *(float4*)(pRw + i0) = make_float4(ar0[0], ar0[1], ar0[2], ar0[3]);
    *(float4*)(pZw + i0) = make_float4(az0[0], az0[1], az0[2], az0[3]);
    *(float4*)(pNw + i0) = make_float4(an0[0], an0[1], an0[2], an0[3]);
    *(float4*)(pRw + i1) = make_float4(ar1[0], ar1[1], ar1[2], ar1[3]);
    *(float4*)(pZw + i1) = make_float4(az1[0], az1[1], az1[2], az1[3]);
    *(float4*)(pNw + i1) = make_float4(an1[0], an1[1], an1[2], an1[3]);
  }
}

// ---------- fused latent + hypernet layers 1-2 ----------
__global__ __launch_bounds__(256) void latent_hyper_k(
    const float* __restrict__ h_enc,
    const float* __restrict__ to_mu, const float* __restrict__ to_lsig,
    const float* __restrict__ lsig_bias, const float* __restrict__ eps,
    const float* __restrict__ W1, const float* __restrict__ b1,
    const float* __restrict__ W2, const float* __restrict__ b2,
    float* __restrict__ out_mu, float* __restrict__ out_lsig,
    float* __restrict__ a2out) {
  int b = blockIdx.x;
  __shared__ float hs[1024];
  __shared__ float zv[8];
  __shared__ float a1[1024];
  for (int i = threadIdx.x; i < 1024; i += 256) hs[i] = h_enc[b * 1024 + i];
  __syncthreads();
  int g = threadIdx.x >> 5, s = threadIdx.x & 31;
  if (g < nK) {
    float am = 0.f, as_ = 0.f;
    for (int h = s; h < 1024; h += 32) {
      float hv = hs[h];
      am += hv * to_mu[h * nK + g];
      as_ += hv * to_lsig[h * nK + g];
    }
    #pragma unroll
    for (int m = 16; m >= 1; m >>= 1) { am += __shfl_xor(am, m); as_ += __shfl_xor(as_, m); }
    if (s == 0) {
      float ls = as_ + lsig_bias[g];
      out_mu[b * nK + g] = am;
      out_lsig[b * nK + g] = ls;
      zv[g] = am + eps[b * nK + g] * __expf(ls);
    }
  }
  __syncthreads();
  for (int j = threadIdx.x; j < 1024; j += 256) {
    float acc = b1[j];
    #pragma unroll
    for (int i = 0; i < nK; ++i) acc += zv[i] * W1[i * 1024 + j];
    a1[j] = tanhf(acc);
  }
  __syncthreads();
  int l = threadIdx.x >> 3, s8 = threadIdx.x & 7;
  if (l < 30) {
    float acc = 0.f;
    for (int j = s8; j < 1024; j += 8) acc += a1[j] * W2[j * 30 + l];
    acc += __shfl_xor(acc, 4);
    acc += __shfl_xor(acc, 2);
    acc += __shfl_xor(acc, 1);
    if (s8 == 0) a2out[b * 30 + l] = acc + b2[l];
  }
}

// ---------- psi materialization: 2 outputs/thread, vectorized ----------
__global__ __launch_bounds__(256) void psi_k(const float* __restrict__ a2,
                                             const float* __restrict__ W3, const float* __restrict__ b3,
                                             unsigned short* __restrict__ WhhB, float* __restrict__ Rest) {
  __shared__ float sa[64 * 30];
  for (int i = threadIdx.x; i < 64 * 30; i += 256) sa[i] = a2[i];
  long n0 = ((long)blockIdx.x * 256 + threadIdx.x) * 2;
  __syncthreads();
  if (n0 >= N_PSI) return;
  float2 w[30];
  #pragma unroll
  for (int l = 0; l < 30; ++l) w[l] = *(const float2*)(W3 + (long)l * N_PSI + n0);
  float2 bb = *(const float2*)(b3 + n0);
  bool isWhh = (n0 < SZ_WHH);
  for (int b = 0; b < 64; ++b) {
    float a0 = bb.x, a1v = bb.y;
    const float* ab = &sa[b * 30];
    #pragma unroll
    for (int l = 0; l < 30; ++l) { float av = ab[l]; a0 += av * w[l].x; a1v += av * w[l].y; }
    if (isWhh) {
      us2 o; o[0] = f2b(a0); o[1] = f2b(a1v);
      *(us2*)(WhhB + (long)b * SZ_WHH + n0) = o;
    } else {
      *(float2*)(Rest + (long)b * REST_SZ + (n0 - SZ_WHH)) = make_float2(a0, a1v);
    }
  }
}

// ---------- int8 Whh quantization (per-sample, per-column scale) ----------
// pass 1: partial column max over 256-row quarters. grid 256: b=blk>>2, rq=blk&3
__global__ __launch_bounds__(256) void wmax_k(const unsigned short* __restrict__ WhhB,
                                              float* __restrict__ pmax) {
  int b = blockIdx.x >> 2, rq = blockIdx.x & 3;
  int k0 = threadIdx.x * 4;
  float m0 = 0.f, m1 = 0.f, m2 = 0.f, m3 = 0.f;
  const unsigned short* W = WhhB + (long)b * SZ_WHH + (long)rq * 256 * 1024 + k0;
  #pragma unroll 4
  for (int j = 0; j < 256; ++j) {
    us4 w = *(const us4*)(W + (long)j * 1024);
    m0 = fmaxf(m0, fabsf(b2f(w[0])));
    m1 = fmaxf(m1, fabsf(b2f(w[1])));
    m2 = fmaxf(m2, fabsf(b2f(w[2])));
    m3 = fmaxf(m3, fabsf(b2f(w[3])));
  }
  *(float4*)(pmax + ((long)b * 4 + rq) * 1024 + k0) = make_float4(m0, m1, m2, m3);
}

// pass 2: reduce quarters -> scale = max/127. grid 64
__global__ __launch_bounds__(256) void wscale_k(const float* __restrict__ pmax,
                                                float* __restrict__ wsc) {
  int b = blockIdx.x;
  int k0 = threadIdx.x * 4;
  float4 a = *(const float4*)(pmax + ((long)b * 4 + 0) * 1024 + k0);
  float4 c = *(const float4*)(pmax + ((long)b * 4 + 1) * 1024 + k0);
  float4 d = *(const float4*)(pmax + ((long)b * 4 + 2) * 1024 + k0);
  float4 e = *(const float4*)(pmax + ((long)b * 4 + 3) * 1024 + k0);
  float m0 = fmaxf(fmaxf(a.x, c.x), fmaxf(d.x, e.x));
  float m1 = fmaxf(fmaxf(a.y, c.y), fmaxf(d.y, e.y));
  float m2 = fmaxf(fmaxf(a.z, c.z), fmaxf(d.z, e.z));
  float m3 = fmaxf(fmaxf(a.w, c.w), fmaxf(d.w, e.w));
  float s0 = (m0 > 0.f) ? m0 / 127.f : 1.f;
  float s1 = (m1 > 0.f) ? m1 / 127.f : 1.f;
  float s2 = (m2 > 0.f) ? m2 / 127.f : 1.f;
  float s3 = (m3 > 0.f) ? m3 / 127.f : 1.f;
  *(float4*)(wsc + (long)b * 1024 + k0) = make_float4(s0, s1, s2, s3);
}

// pass 3: quantize. grid 256: b=blk>>2, rq=blk&3
__global__ __launch_bounds__(256) void wquant_k(const unsigned short* __restrict__ WhhB,
                                                const float* __restrict__ wsc,
                                                char* __restrict__ Q8) {
  int b = blockIdx.x >> 2, rq = blockIdx.x & 3;
  int k0 = threadIdx.x * 4;
  float4 s = *(const float4*)(wsc + (long)b * 1024 + k0);
  float i0 = 1.f / s.x, i1 = 1.f / s.y, i2 = 1.f / s.z, i3 = 1.f / s.w;
  const unsigned short* W = WhhB + (long)b * SZ_WHH + (long)rq * 256 * 1024 + k0;
  char* Q = Q8 + (long)b * SZ_WHH + (long)rq * 256 * 1024 + k0;
  #pragma unroll 4
  for (int j = 0; j < 256; ++j) {
    us4 w = *(const us4*)(W + (long)j * 1024);
    int q0 = __float2int_rn(b2f(w[0]) * i0);
    int q1 = __float2int_rn(b2f(w[1]) * i1);
    int q2 = __float2int_rn(b2f(w[2]) * i2);
    int q3 = __float2int_rn(b2f(w[3]) * i3);
    q0 = min(127, max(-127, q0)); q1 = min(127, max(-127, q1));
    q2 = min(127, max(-127, q2)); q3 = min(127, max(-127, q3));
    *(char4*)(Q + (long)j * 1024) = make_char4((char)q0, (char)q1, (char)q2, (char)q3);
  }
}

// ---------- decoder fused step (r4 structure, int8 Whh) ----------
__global__ __launch_bounds__(256) void dec_step_q8_k(
    const char* __restrict__ Q8,               // [B][1024][1024] int8
    const float* __restrict__ Wsc,             // [B][1024] per-col scale
    const unsigned short* __restrict__ gWhhB,  // [1024][2048] bf16
    const unsigned short* __restrict__ gxD,    // [T][B][2048] bf16 (incl gbias)
    const unsigned short* __restrict__ xWb,    // [T][B][1024] bf16
    const float* __restrict__ Rest,
    float* __restrict__ decS,                  // [B][T][1024]
    const float* __restrict__ pZr, const float* __restrict__ pRr, const float* __restrict__ pWr,
    float* __restrict__ pZw, float* __restrict__ pRw, float* __restrict__ pWw,
    int t) {
  int c = blockIdx.x & (NCH - 1);
  int sp = blockIdx.x >> 4;
  int b0 = sp * 2, b1 = b0 + 1;
  __shared__ float h0s[CHR], h1s[CHR];

  int v = threadIdx.x;
  if (v < 2 * CHR) {
    int hi = v >> 6;
    int bb = hi ? b1 : b0;
    int k = c * CHR + (v & 63);
    float sz = 0.f, sr = 0.f, sw = 0.f;
    float hold = 0.f;
    if (t > 0) {
      #pragma unroll
      for (int cc = 0; cc < NCH; ++cc) {
        long base = ((long)cc * 64 + bb) * 1024 + k;
        sz += pZr[base]; sr += pRr[base]; sw += pWr[base];
      }
      hold = decS[((long)bb * nT + (t - 1)) * 1024 + k];
    }
    long gb = ((long)t * 64 + bb) * 2048;
    float gz = b2f(gxD[gb + k]), gr = b2f(gxD[gb + 1024 + k]);
    float z = sigm(gz + sz);
    float r = sigm(gr + sr);
    float hW = sw + Rest[(long)bb * REST_SZ + R_BH + k];
    float xw = b2f(xWb[((long)t * 64 + bb) * 1024 + k]);
    float eta = tanhf(xw + r * tanhf(hW));
    float hnew = z * hold + (1.f - z) * eta;
    decS[((long)bb * nT + t) * 1024 + k] = hnew;
    if (hi) h1s[v & 63] = hnew; else h0s[v & 63] = hnew;
  }
  __syncthreads();

  if (t < nT - 1) {
    int k0 = threadIdx.x * 4;
    float az0[4] = {}, ar0[4] = {}, aw0[4] = {}, az1[4] = {}, ar1[4] = {}, aw1[4] = {};
    const unsigned short* G = gWhhB + (long)(c * CHR) * 2048 + k0;
    const char* Q0 = Q8 + (long)b0 * SZ_WHH + (long)(c * CHR) * 1024 + k0;
    const char* Q1 = Q8 + (long)b1 * SZ_WHH + (long)(c * CHR) * 1024 + k0;
    #pragma unroll 4
    for (int j = 0; j < CHR; ++j) {
      us4 wz = *(const us4*)(G + (long)j * 2048);
      us4 wr = *(const us4*)(G + (long)j * 2048 + 1024);
      char4 q0 = *(const char4*)(Q0 + (long)j * 1024);
      char4 q1 = *(const char4*)(Q1 + (long)j * 1024);
      float hv0 = h0s[j], hv1 = h1s[j];
      float f00 = (float)q0.x, f01 = (float)q0.y, f02 = (float)q0.z, f03 = (float)q0.w;
      float f10 = (float)q1.x, f11 = (float)q1.y, f12 = (float)q1.z, f13 = (float)q1.w;
      #pragma unroll
      for (int q = 0; q < 4; ++q) {
        float fz = b2f(wz[q]), fr = b2f(wr[q]);
        az0[q] += hv0 * fz; ar0[q] += hv0 * fr;
        az1[q] += hv1 * fz; ar1[q] += hv1 * fr;
      }
      aw0[0] += hv0 * f00; aw0[1] += hv0 * f01; aw0[2] += hv0 * f02; aw0[3] += hv0 * f03;
      aw1[0] += hv1 * f10; aw1[1] += hv1 * f11; aw1[2] += hv1 * f12; aw1[3] += hv1 * f13;
    }
    float4 s0v = *(const float4*)(Wsc + (long)b0 * 1024 + k0);
    float4 s1v = *(const float4*)(Wsc + (long)b1 * 1024 + k0);
    aw0[0] *= s0v.x; aw0[1] *= s0v.y; aw0[2] *= s0v.z; aw0[3] *= s0v.w;
    aw1[0] *= s1v.x; aw1[1] *= s1v.y; aw1[2] *= s1v.z; aw1[3] *= s1v.w;
    long i0 = ((long)c * 64 + b0) * 1024 + k0;
    long i1 = i0 + 1024;
    *(float4*)(pZw + i0) = make_float4(az0[0], az0[1], az0[2], az0[3]);
    *(float4*)(pRw + i0) = make_float4(ar0[0], ar0[1], ar0[2], ar0[3]);
    *(float4*)(pWw + i0) = make_float4(aw0[0], aw0[1], aw0[2], aw0[3]);
    *(float4*)(pZw + i1) = make_float4(az1[0], az1[1], az1[2], az1[3]);
    *(float4*)(pRw + i1) = make_float4(ar1[0], ar1[1], ar1[2], ar1[3]);
    *(float4*)(pWw + i1) = make_float4(aw1[0], aw1[1], aw1[2], aw1[3]);
  }
}

// ---------- decoder fused step (r4 exact, bf16 fallback) ----------
__global__ __launch_bounds__(256) void dec_step_bf_k(
    const unsigned short* __restrict__ WhhB,
    const unsigned short* __restrict__ gWhhB,
    const unsigned short* __restrict__ gxD,
    const unsigned short* __restrict__ xWb,
    const float* __restrict__ Rest,
    float* __restrict__ decS,
    const float* __restrict__ pZr, const float* __restrict__ pRr, const float* __restrict__ pWr,
    float* __restrict__ pZw, float* __restrict__ pRw, float* __restrict__ pWw,
    int t) {
  int c = blockIdx.x & (NCH - 1);
  int sp = blockIdx.x >> 4;
  int b0 = sp * 2, b1 = b0 + 1;
  __shared__ float h0s[CHR], h1s[CHR];

  int v = threadIdx.x;
  if (v < 2 * CHR) {
    int hi = v >> 6;
    int bb = hi ? b1 : b0;
    int k = c * CHR + (v & 63);
    float sz = 0.f, sr = 0.f, sw = 0.f;
    float hold = 0.f;
    if (t > 0) {
      #pragma unroll
      for (int cc = 0; cc < NCH; ++cc) {
        long base = ((long)cc * 64 + bb) * 1024 + k;
        sz += pZr[base]; sr += pRr[base]; sw += pWr[base];
      }
      hold = decS[((long)bb * nT + (t - 1)) * 1024 + k];
    }
    long gb = ((long)t * 64 + bb) * 2048;
    float gz = b2f(gxD[gb + k]), gr = b2f(gxD[gb + 1024 + k]);
    float z = sigm(gz + sz);
    float r = sigm(gr + sr);
    float hW = sw + Rest[(long)bb * REST_SZ + R_BH + k];
    float xw = b2f(xWb[((long)t * 64 + bb) * 1024 + k]);
    float eta = tanhf(xw + r * tanhf(hW));
    float hnew = z * hold + (1.f - z) * eta;
    decS[((long)bb * nT + t) * 1024 + k] = hnew;
    if (hi) h1s[v & 63] = hnew; else h0s[v & 63] = hnew;
  }
  __syncthreads();

  if (t < nT - 1) {
    int k0 = threadIdx.x * 4;
    float az0[4] = {}, ar0[4] = {}, aw0[4] = {}, az1[4] = {}, ar1[4] = {}, aw1[4] = {};
    const unsigned short* G = gWhhB + (long)(c * CHR) * 2048 + k0;
    const unsigned short* W0 = WhhB + (long)b0 * SZ_WHH + (long)(c * CHR) * 1024 + k0;
    const unsigned short* W1p = WhhB + (long)b1 * SZ_WHH + (long)(c * CHR) * 1024 + k0;
    #pragma unroll 4
    for (int j = 0; j < CHR; ++j) {
      us4 wz = *(const us4*)(G + (long)j * 2048);
      us4 wr = *(const us4*)(G + (long)j * 2048 + 1024);
      us4 w0 = *(const us4*)(W0 + (long)j * 1024);
      us4 w1 = *(const us4*)(W1p + (long)j * 1024);
      float hv0 = h0s[j], hv1 = h1s[j];
      #pragma unroll
      for (int q = 0; q < 4; ++q) {
        float fz = b2f(wz[q]), fr = b2f(wr[q]), f0 = b2f(w0[q]), f1 = b2f(w1[q]);
        az0[q] += hv0 * fz; ar0[q] += hv0 * fr; aw0[q] += hv0 * f0;
        az1[q] += hv1 * fz; ar1[q] += hv1 * fr; aw1[q] += hv1 * f1;
      }
    }
    long i0 = ((long)c * 64 + b0) * 1024 + k0;
    long i1 = i0 + 1024;
    *(float4*)(pZw + i0) = make_float4(az0[0], az0[1], az0[2], az0[3]);
    *(float4*)(pRw + i0) = make_float4(ar0[0], ar0[1], ar0[2], ar0[3]);
    *(float4*)(pWw + i0) = make_float4(aw0[0], aw0[1], aw0[2], aw0[3]);
    *(float4*)(pZw + i1) = make_float4(az1[0], az1[1], az1[2], az1[3]);
    *(float4*)(pRw + i1) = make_float4(ar1[0], ar1[1], ar1[2], ar1[3]);
    *(float4*)(pWw + i1) = make_float4(aw1[0], aw1[1], aw1[2], aw1[3]);
  }
}

// ---------- readout: block = (sample, 8 timesteps), C stripe reused ----------
__global__ __launch_bounds__(256) void readout_k(
    const float* __restrict__ dec_seq, const float* __restrict__ inputs,
    const float* __restrict__ Rest, float* __restrict__ yhats) {
  int b = blockIdx.x >> 3;
  int tg = blockIdx.x & 7;
  __shared__ float ss[8][1024];
  __shared__ float part[4][8][64];
  for (int i = threadIdx.x; i < 8 * 1024; i += 256)
    ss[i >> 10][i & 1023] = dec_seq[((long)b * nT + tg * 8 + (i >> 10)) * 1024 + (i & 1023)];
  __syncthreads();
  int m = threadIdx.x & 63, hq = threadIdx.x >> 6;
  const float* C = Rest + (long)b * REST_SZ + R_C;
  float acc[8] = {};
  for (int h = hq * 256; h < hq * 256 + 256; ++h) {
    float cv = C[(long)h * 64 + m];
    #pragma unroll
    for (int tt = 0; tt < 8; ++tt) acc[tt] += ss[tt][h] * cv;
  }
  #pragma unroll
  for (int tt = 0; tt < 8; ++tt) part[hq][tt][m] = acc[tt];
  __syncthreads();
  const float* D = Rest + (long)b * REST_SZ + R_D;
  for (int o = threadIdx.x; o < 512; o += 256) {
    int tt = o >> 6, mm = o & 63;
    float a = part[0][tt][mm] + part[1][tt][mm] + part[2][tt][mm] + part[3][tt][mm];
    long bt = (long)b * nT + tg * 8 + tt;
    if (mm < 8) {
      a += inputs[bt * 8 + mm];
    } else {
      #pragma unroll
      for (int i = 0; i < 8; ++i) a += inputs[bt * 8 + i] * D[i * 56 + (mm - 8)];
    }
    yhats[bt * 64 + mm] = a;
  }
}

__global__ void copy_states_k(const float* __restrict__ dec_seq, float* __restrict__ states) {
  int i = blockIdx.x * 256 + threadIdx.x;
  int b = i >> 10, h = i & 1023;
  states[i] = dec_seq[((long)b * nT + (nT - 1)) * 1024 + h];
}

extern "C" void kernel_launch(void* const* d_in, const int* in_sizes, int n_in,
                              void* d_out, int out_size, void* d_ws, size_t ws_size,
                              hipStream_t stream) {
  const float* inputs  = (const float*)d_in[0];
  const float* outputs = (const float*)d_in[1];
  const float* eps     = (const float*)d_in[2];
  const float* enc_Wih = (const float*)d_in[3];
  const float* enc_Whh = (const float*)d_in[4];
  const float* enc_bih = (const float*)d_in[5];
  const float* enc_bhh = (const float*)d_in[6];
  const float* to_mu   = (const float*)d_in[7];
  const float* to_lsig = (const float*)d_in[8];
  const float* lsig_b  = (const float*)d_in[9];
  const float* W1 = (const float*)d_in[10];
  const float* b1 = (const float*)d_in[11];
  const float* W2 = (const float*)d_in[12];
  const float* b2 = (const float*)d_in[13];
  const float* W3 = (const float*)d_in[14];
  const float* b3 = (const float*)d_in[15];
  const float* gWih  = (const float*)d_in[16];
  const float* gWhh  = (const float*)d_in[17];
  const float* gbias = (const float*)d_in[18];

  char* ws = (char*)d_ws;
  size_t off = 0;
  auto alloc = [&](size_t bytes) { size_t o = off; off = (off + bytes + 255) & ~(size_t)255; return o; };
  size_t oWhhB   = alloc(64ull * SZ_WHH * 2);        // bf16 per-sample Whh
  size_t oRest   = alloc(64ull * REST_SZ * 4);       // fp32 psi remainder
  size_t ogWhhB  = alloc(1024ull * 2048 * 2);        // bf16 gru_Whh
  size_t oWtWhhB = alloc(1024ull * 3072 * 2);        // bf16 enc_Whh^T
  size_t oWtWihB = alloc(64ull * 3072 * 2);          // bf16 enc_Wih^T
  size_t ogxE    = alloc(64ull * 64 * 3072 * 2);     // bf16 encoder gx (incl bih)
  size_t ogxD    = alloc(64ull * 64 * 2048 * 2);     // bf16 decoder gx (incl gbias)
  size_t oxWb    = alloc(64ull * 64 * 1024 * 2);     // bf16 x@Wih_b
  size_t opA     = alloc((size_t)2 * PHALF * 4);     // dbuf partials
  size_t opB     = alloc((size_t)2 * PHALF * 4);
  size_t opC     = alloc((size_t)2 * PHALF * 4);
  size_t ohA     = alloc(64ull * 1024 * 4);          // encoder running h
  size_t oDec    = alloc(64ull * 64 * 1024 * 4);
  size_t oA2     = alloc(64 * 30 * 4);
  // optional int8 region (fallback to bf16 if workspace too small)
  size_t oQ8     = alloc(64ull * SZ_WHH);            // int8 Whh (67 MB)
  size_t oPmax   = alloc(64ull * 4 * 1024 * 4);      // per-quarter col max
  size_t oWsc    = alloc(64ull * 1024 * 4);          // per-col scale
  bool useQ8 = (off <= ws_size);
  (void)in_sizes; (void)n_in; (void)out_size;

  unsigned short* WhhB   = (unsigned short*)(ws + oWhhB);
  float*          Rest   = (float*)(ws + oRest);
  unsigned short* gWhhB  = (unsigned short*)(ws + ogWhhB);
  unsigned short* WtWhhB = (unsigned short*)(ws + oWtWhhB);
  unsigned short* WtWihB = (unsigned short*)(ws + oWtWihB);
  unsigned short* gxE    = (unsigned short*)(ws + ogxE);
  unsigned short* gxD    = (unsigned short*)(ws + ogxD);
  unsigned short* xWb    = (unsigned short*)(ws + oxWb);
  float* pA   = (float*)(ws + opA);
  float* pB   = (float*)(ws + opB);
  float* pC   = (float*)(ws + opC);
  float* hA   = (float*)(ws + ohA);
  float* decS = (float*)(ws + oDec);
  float* a2   = (float*)(ws + oA2);
  char*  Q8   = (char*)(ws + oQ8);
  float* pmax = (float*)(ws + oPmax);
  float* wsc  = (float*)(ws + oWsc);

  float* out    = (float*)d_out;
  float* out_yh = out;                 // 262144
  float* out_mu = out + 262144;        // 448
  float* out_ls = out + 262144 + 448;  // 448
  float* out_st = out + 262144 + 896;  // 65536

  // 1) weight preprocessing (bf16)
  transpose_bf16_k<<<dim3(32, 96), dim3(32, 8), 0, stream>>>(enc_Whh, WtWhhB, 3072, 1024);
  transpose_bf16_k<<<dim3(2, 96),  dim3(32, 8), 0, stream>>>(enc_Wih, WtWihB, 3072, 64);
  cvt_bf16_k<<<(int)((1024ull * 2048 + 255) / 256), 256, 0, stream>>>(gWhh, gWhhB, 1024 * 2048);

  // 2) bulk encoder gx
  enc_gx_k<<<dim3(12, 64), 256, 0, stream>>>(outputs, WtWihB, enc_bih, gxE);

  // 3) encoder recurrence (r4 structure)
  for (int t = 0; t < nT; ++t) {
    int rp = t & 1, wp = (t + 1) & 1;
    enc_step_k<<<512, 256, 0, stream>>>(WtWhhB, gxE, enc_bhh, hA,
        pA + (size_t)rp * PHALF, pB + (size_t)rp * PHALF, pC + (size_t)rp * PHALF,
        pA + (size_t)wp * PHALF, pB + (size_t)wp * PHALF, pC + (size_t)wp * PHALF, t);
  }

  // 4) latent+hypernet fused, then psi
  latent_hyper_k<<<64, 256, 0, stream>>>(hA, to_mu, to_lsig, lsig_b, eps,
                                         W1, b1, W2, b2, out_mu, out_ls, a2);
  psi_k<<<(int)((N_PSI / 2 + 255) / 256), 256, 0, stream>>>(a2, W3, b3, WhhB, Rest);

  // 4b) int8 quantization of Whh (per-sample per-column scale)
  if (useQ8) {
    wmax_k<<<256, 256, 0, stream>>>(WhhB, pmax);
    wscale_k<<<64, 256, 0, stream>>>(pmax, wsc);
    wquant_k<<<256, 256, 0, stream>>>(WhhB, wsc, Q8);
  }

  // 5) bulk decoder gx and x@Wih_b
  dec_gx_k<<<dim3(8, 64), 256, 0, stream>>>(inputs, gWih, gbias, gxD);
  xW_k<<<dim3(4, 64), 256, 0, stream>>>(inputs, Rest, xWb);

  // 6) decoder recurrence (r4 structure; int8 Whh if workspace allows)
  for (int t = 0; t < nT; ++t) {
    int rp = t & 1, wp = (t + 1) & 1;
    if (useQ8) {
      dec_step_q8_k<<<512, 256, 0, stream>>>(Q8, wsc, gWhhB, gxD, xWb, Rest, decS,
          pA + (size_t)rp * PHALF, pB + (size_t)rp * PHALF, pC + (size_t)rp * PHALF,
          pA + (size_t)wp * PHALF, pB + (size_t)wp * PHALF, pC + (size_t)wp * PHALF, t);
    } else {
      dec_step_bf_k<<<512, 256, 0, stream>>>(WhhB, gWhhB, gxD, xWb, Rest, decS,
          pA + (size_t)rp * PHALF, pB + (size_t)rp * PHALF, pC + (size_t)rp * PHALF,
          pA + (size_t)wp * PHALF, pB + (size_t)wp * PHALF, pC + (size_t)wp * PHALF, t);
    }
  }

  // 7) readout + states
  readout_k<<<512, 256, 0, stream>>>(decS, inputs, Rest, out_yh);
  copy_states_k<<<256, 256, 0, stream>>>(decS, out_st);
}